// Round 1
// baseline (258.382 us; speedup 1.0000x reference)
//
#include <hip/hip_runtime.h>

// Problem constants: N=32, C=3, H=W=512, SCALE=1 -> OUT=512, A=512,
// DENSE=4 -> thr0 = 4.0, ITERS=5.
#define NB   32
#define NC   3
#define HH   512
#define WW   512
#define AA   512
#define OUT  512

// ---------------- wave-level primitives (64-lane) ---------------------------
__device__ __forceinline__ float wave_sum(float v) {
#pragma unroll
    for (int m = 32; m > 0; m >>= 1) v += __shfl_xor(v, m, 64);
    return v;
}
__device__ __forceinline__ float wave_max(float v) {
#pragma unroll
    for (int m = 32; m > 0; m >>= 1) v = fmaxf(v, __shfl_xor(v, m, 64));
    return v;
}

// ---------------- kernel 1: iterative clip + inverse CDF --------------------
// ONE WAVE per batch n. Each lane owns 8 contiguous elements in registers.
// All reductions + the scan are in-register shuffles: the ~100-barrier chain
// of the previous version collapses to a single (1-wave, ~free) __syncthreads
// that publishes the cumsum to LDS for the binary search.
__global__ __launch_bounds__(64) void clip_cdf_kernel(
    const float* __restrict__ attx, const float* __restrict__ atty,
    float* __restrict__ px, float* __restrict__ py)
{
    __shared__ float csx[AA];
    __shared__ float csy[AA];

    const int n    = blockIdx.x;
    const int lane = threadIdx.x;          // 0..63

    // load 8 elements per lane, coalesced float4 pairs
    float ax[8], ay[8];
    {
        const float4* bx = (const float4*)(attx + n * AA + lane * 8);
        const float4* by = (const float4*)(atty + n * AA + lane * 8);
        float4 x0 = bx[0], x1 = bx[1];
        float4 yv0 = by[0], yv1 = by[1];
        ax[0]=x0.x; ax[1]=x0.y; ax[2]=x0.z; ax[3]=x0.w;
        ax[4]=x1.x; ax[5]=x1.y; ax[6]=x1.z; ax[7]=x1.w;
        ay[0]=yv0.x; ay[1]=yv0.y; ay[2]=yv0.z; ay[3]=yv0.w;
        ay[4]=yv1.x; ay[5]=yv1.y; ay[6]=yv1.z; ay[7]=yv1.w;
    }

    // normalize * OUT
    {
        float lsx = 0.0f, lsy = 0.0f;
#pragma unroll
        for (int k = 0; k < 8; ++k) { lsx += ax[k]; lsy += ay[k]; }
        const float sx = wave_sum(lsx);
        const float sy = wave_sum(lsy);
#pragma unroll
        for (int k = 0; k < 8; ++k) {
            ax[k] = ax[k] / sx * (float)OUT;
            ay[k] = ay[k] / sy * (float)OUT;
        }
    }

    // 5 clip iterations — all in-register, no barriers
#pragma unroll
    for (int it = 0; it < 5; ++it) {
        float lmx = ax[0], lmy = ay[0];
#pragma unroll
        for (int k = 1; k < 8; ++k) { lmx = fmaxf(lmx, ax[k]); lmy = fmaxf(lmy, ay[k]); }
        const float mx = wave_max(lmx);
        const float my = wave_max(lmy);
        float tv = fminf(mx, my);
        if (it == 0) tv = fminf(tv, 4.0f);     // thr0 = DENSE*OUT/A

        float lsx = 0.0f, lsy = 0.0f;
#pragma unroll
        for (int k = 0; k < 8; ++k) {
            ax[k] = fminf(ax[k], tv); lsx += ax[k];
            ay[k] = fminf(ay[k], tv); lsy += ay[k];
        }
        const float sxs = wave_sum(lsx);
        const float sys = wave_sum(lsy);
        const float addx = ((float)OUT - sxs) * (1.0f / (float)AA);
        const float addy = ((float)OUT - sys) * (1.0f / (float)AA);
#pragma unroll
        for (int k = 0; k < 8; ++k) { ax[k] += addx; ay[k] += addy; }
    }

    // inclusive scan: in-lane sequential prefix + wave shfl_up scan of totals
    float prex[8], prey[8];
    float runx = 0.0f, runy = 0.0f;
#pragma unroll
    for (int k = 0; k < 8; ++k) {
        runx += ax[k]; prex[k] = runx;
        runy += ay[k]; prey[k] = runy;
    }
    const float ltx = runx, lty = runy;
    float sxi = ltx, syi = lty;
#pragma unroll
    for (int off = 1; off < 64; off <<= 1) {
        const float tx = __shfl_up(sxi, off, 64);
        const float ty = __shfl_up(syi, off, 64);
        if (lane >= off) { sxi += tx; syi += ty; }
    }
    const float exx  = sxi - ltx;            // exclusive prefix of lane totals
    const float exy  = syi - lty;
    const float totx = __shfl(sxi, 63, 64);
    const float toty = __shfl(syi, 63, 64);

#pragma unroll
    for (int k = 0; k < 8; ++k) {
        csx[lane * 8 + k] = exx + prex[k];
        csy[lane * 8 + k] = exy + prey[k];
    }
    __syncthreads();   // 1-wave block: essentially an lgkmcnt drain

    const float stepx = totx * (1.0f / (float)OUT);
    const float stepy = toty * (1.0f / (float)OUT);

    float rx[8], ry[8];
#pragma unroll
    for (int k = 0; k < 8; ++k) {
        const int e = lane * 8 + k;

        // searchsorted left on csx
        {
            const float tk = ((float)e + 0.5f) * stepx;
            int lo = 0, hi = AA;
            while (lo < hi) {
                const int mid = (lo + hi) >> 1;
                if (csx[mid] < tk) lo = mid + 1; else hi = mid;
            }
            int j = lo > AA - 1 ? AA - 1 : lo;
            const float cp   = (j > 0) ? csx[j - 1] : 0.0f;
            const float dens = csx[j] - cp;
            const float p    = (float)j + (tk - cp) / fmaxf(dens, 1e-6f);
            rx[k] = 2.0f * p / (float)AA - 1.0f;
        }
        // searchsorted left on csy
        {
            const float tk = ((float)e + 0.5f) * stepy;
            int lo = 0, hi = AA;
            while (lo < hi) {
                const int mid = (lo + hi) >> 1;
                if (csy[mid] < tk) lo = mid + 1; else hi = mid;
            }
            int j = lo > AA - 1 ? AA - 1 : lo;
            const float cp   = (j > 0) ? csy[j - 1] : 0.0f;
            const float dens = csy[j] - cp;
            const float p    = (float)j + (tk - cp) / fmaxf(dens, 1e-6f);
            ry[k] = 2.0f * p / (float)AA - 1.0f;
        }
    }

    float4* opx = (float4*)(px + n * OUT + lane * 8);
    float4* opy = (float4*)(py + n * OUT + lane * 8);
    opx[0] = make_float4(rx[0], rx[1], rx[2], rx[3]);
    opx[1] = make_float4(rx[4], rx[5], rx[6], rx[7]);
    opy[0] = make_float4(ry[0], ry[1], ry[2], ry[3]);
    opy[1] = make_float4(ry[4], ry[5], ry[6], ry[7]);
}

// ---------------- kernel 2: grid build + bilinear sample -------------------
// Changes vs previous: (a) chunked XCD swizzle so consecutive output rows
// (which share a staged data row) run on the same XCD's L2; (b) each thread
// produces 2 adjacent outputs -> float2 px loads, float2 sampled stores,
// float4 grid stores; single pass, no rep loop.
__global__ __launch_bounds__(256) void sample_kernel(
    const float* __restrict__ data, const float* __restrict__ px,
    const float* __restrict__ py, float* __restrict__ sampled,
    float2* __restrict__ grid)
{
    __shared__ float lrow[6][WW];   // 12 KB: rows (y0,c0..2), (y1,c0..2)

    // bijective chunked XCD swizzle: 16384 blocks, 8 XCDs, 2048-block chunks.
    int b = blockIdx.x;
    b = (b & 7) * ((NB * OUT) / 8) + (b >> 3);
    const int n = b >> 9;                // / 512
    const int i = b & (OUT - 1);

    const int tid = threadIdx.x;

    const float gy  = py[n * OUT + i];
    const float iy  = (gy + 1.0f) * 0.5f * (float)(HH - 1);
    const float y0f = floorf(iy);
    const float wy  = iy - y0f;
    int y0 = (int)y0f;
    y0 = max(0, min(y0, HH - 1));
    const int y1 = min(y0 + 1, HH - 1);

    const float* dbase = data + (size_t)n * NC * HH * WW;

    // stage 6 rows: 768 float4s over 256 threads (3 each), coalesced
#pragma unroll
    for (int k = 0; k < 3; ++k) {
        const int idx = tid + k * 256;       // 0..767
        const int row = idx >> 7;            // 0..5 (128 float4 per row)
        const int q   = idx & 127;           // float4 index within row
        const int c   = (row < 3) ? row : row - 3;
        const int y   = (row < 3) ? y0 : y1;
        const float4 v = ((const float4*)(dbase + ((size_t)c * HH + y) * WW))[q];
        ((float4*)&lrow[row][0])[q] = v;
    }
    __syncthreads();

    float*  sbase  = sampled + (size_t)n * NC * HH * WW + (size_t)i * WW;
    float4* gbase4 = (float4*)(grid + ((size_t)n * OUT + i) * OUT);
    const float omwy = 1.0f - wy;

    // two adjacent outputs per thread: j = 2*tid, 2*tid+1
    const float2 g2 = ((const float2*)(px + n * OUT))[tid];

    const float ix0 = (g2.x + 1.0f) * 0.5f * (float)(WW - 1);
    const float ix1 = (g2.y + 1.0f) * 0.5f * (float)(WW - 1);
    const float xf0 = floorf(ix0);
    const float xf1 = floorf(ix1);
    const float wx0 = ix0 - xf0;
    const float wx1 = ix1 - xf1;
    int a0 = (int)xf0; a0 = max(0, min(a0, WW - 1)); const int b0 = min(a0 + 1, WW - 1);
    int a1 = (int)xf1; a1 = max(0, min(a1, WW - 1)); const int b1 = min(a1 + 1, WW - 1);
    const float omx0 = 1.0f - wx0;
    const float omx1 = 1.0f - wx1;

    gbase4[tid] = make_float4(g2.x, gy, g2.y, gy);

#pragma unroll
    for (int c = 0; c < NC; ++c) {
        const float v00a = lrow[c][a0];
        const float v01a = lrow[c][b0];
        const float v10a = lrow[3 + c][a0];
        const float v11a = lrow[3 + c][b0];
        const float v00b = lrow[c][a1];
        const float v01b = lrow[c][b1];
        const float v10b = lrow[3 + c][a1];
        const float v11b = lrow[3 + c][b1];

        const float topa = v00a * omx0 + v01a * wx0;
        const float bota = v10a * omx0 + v11a * wx0;
        const float topb = v00b * omx1 + v01b * wx1;
        const float botb = v10b * omx1 + v11b * wx1;

        const float ra = topa * omwy + bota * wy;
        const float rb = topb * omwy + botb * wy;

        ((float2*)(sbase + (size_t)c * HH * WW))[tid] = make_float2(ra, rb);
    }
}

extern "C" void kernel_launch(void* const* d_in, const int* in_sizes, int n_in,
                              void* d_out, int out_size, void* d_ws, size_t ws_size,
                              hipStream_t stream) {
    const float* data = (const float*)d_in[0];
    const float* attx = (const float*)d_in[1];
    const float* atty = (const float*)d_in[2];

    float* px = (float*)d_ws;                 // NB*OUT floats
    float* py = px + NB * OUT;                // NB*OUT floats

    float*  out     = (float*)d_out;
    float*  sampled = out;                                        // (N,C,H,W)
    float2* grid    = (float2*)(out + (size_t)NB * NC * HH * WW); // (N,H,W,2)

    clip_cdf_kernel<<<NB, 64, 0, stream>>>(attx, atty, px, py);
    sample_kernel<<<NB * OUT, 256, 0, stream>>>(data, px, py, sampled, grid);
}